// Round 6
// baseline (535.526 us; speedup 1.0000x reference)
//
#include <hip/hip_runtime.h>

// ---------------------------------------------------------------------------
// Attention (Bahdanau): B=32, S=2048, H=512, 2H=1024, 4H=2048
//   u[b,h]      = bias[h] + dot(hidden[b,:1024], W[h,:1024])      (fp32, tiny)
//   scores[b,s] = sum_h v[h]*tanh(u[b,h] + dot(enc[b,s,:], W[h,1024:]))
//   attn        = softmax_s(scores);  context[b,d] = sum_s attn[b,s]*enc[b,s,d]
// R11 = R9/R10 resubmit (both benches died at container/broker level before
// compile; push-time telemetry shows infra degradation 950s->1400s->fail;
// kernel triple-audited: no deadlock, no OOB, no graph-capture violation).
// True deep pipeline in score. Key fact: B staging is WAVE-PRIVATE
// (wave wl DMAs exactly the LDS slice it reads) -> B needs no barrier, only
// own-wave counted vmcnt. Double-buffer A+B (51KB, 3 blk/CU), ONE barrier
// per kk-step. Flight: B = 1 full step (~800cy > L2 300), A-regs = 2 steps
// (~2000cy > HBM 900). Ledger: entry 2 outstanding -> +4 B +2 A = 8; CVT
// waits vmcnt(6); end-of-step vmcnt(2) retires B only; A crosses barrier in
// flight (never vmcnt(0) in loop). XCD swizzle: hh-pairs share enc tile ->
// same XCD for L2 reuse.
// ---------------------------------------------------------------------------

typedef __fp16   half2v __attribute__((ext_vector_type(2)));   // pkrtz result type
typedef _Float16 half8  __attribute__((ext_vector_type(8)));   // MFMA operand type
typedef __attribute__((ext_vector_type(4)))  float f4;
typedef __attribute__((ext_vector_type(16))) float f16v;
typedef __attribute__((ext_vector_type(4)))  unsigned int uint4v;

__device__ __forceinline__ void gload_lds16(const void* g, void* l) {
    __builtin_amdgcn_global_load_lds(
        (const __attribute__((address_space(1))) unsigned int*)g,
        (__attribute__((address_space(3))) unsigned int*)l, 16, 0, 0);
}
__device__ __forceinline__ unsigned int bc2(half2v h) {
    return __builtin_bit_cast(unsigned int, h);
}
// pin issue order of surrounding memory ops (keeps counted vmcnt exact)
#define MEMPIN asm volatile("" ::: "memory")

// ---------------------------------------------------------------------------
// Kernel 1: W2 f16 fragment-major pack (blocks 0..255) + u[b,h] (blocks
// 256..511, coalesced: wave reads whole W rows, hidden staged in LDS,
// 64-lane shuffle reduce). Pack: chunk g = kk*2048 + ntg*128 + kh*64 + l
// holds 8 f16: W[h = ntg*32 + (l&31)][1024 + kk*32 + kh*16 + (l>>5)*8 + j].
// ---------------------------------------------------------------------------
__global__ __launch_bounds__(256) void prep_kernel(
    const float* __restrict__ hidden, const float* __restrict__ W,
    const float* __restrict__ bias, float* __restrict__ u,
    unsigned short* __restrict__ w2) {
    __shared__ float hid_s[1024];
    if (blockIdx.x < 256) {
        int g = blockIdx.x * 256 + threadIdx.x;   // 0..65535 chunks
        int kk = g >> 11, id = g & 2047;
        int ntg = id >> 7, kh = (id >> 6) & 1, l = id & 63;
        int h = (ntg << 5) + (l & 31);
        int kg = 1024 + (kk << 5) + (kh << 4) + ((l >> 5) << 3);
        const float* src = W + (size_t)h * 2048 + kg;
        f4 x0 = *(const f4*)src;
        f4 x1 = *(const f4*)(src + 4);
        half8 vh;
        #pragma unroll
        for (int j = 0; j < 4; ++j) vh[j] = (_Float16)x0[j];      // RN
        #pragma unroll
        for (int j = 0; j < 4; ++j) vh[4 + j] = (_Float16)x1[j];  // RN
        ((half8*)w2)[g] = vh;
    } else {
        // u-part: block = (b, 64-h group). Coalesced W-row reads (1KB/instr).
        const int t = threadIdx.x;
        const int blk = (int)blockIdx.x - 256;
        const int b = blk >> 3, hg = blk & 7;
        ((f4*)hid_s)[t] = ((const f4*)(hidden + ((size_t)b << 10)))[t];
        __syncthreads();
        const int w = t >> 6, lane = t & 63;
        const f4* hid4 = (const f4*)hid_s;
        #pragma unroll 2
        for (int i = 0; i < 16; ++i) {
            int h = (hg << 6) + (w << 4) + i;
            const f4* wr = (const f4*)(W + (size_t)h * 2048);
            float p = 0.f;
            #pragma unroll
            for (int i2 = 0; i2 < 4; ++i2) {
                f4 w4 = wr[lane + (i2 << 6)];
                f4 h4 = hid4[lane + (i2 << 6)];
                p += w4[0]*h4[0] + w4[1]*h4[1] + w4[2]*h4[2] + w4[3]*h4[3];
            }
            #pragma unroll
            for (int off = 1; off < 64; off <<= 1) p += __shfl_xor(p, off);
            if (lane == 0) u[((size_t)b << 9) + h] = bias[h] + p;
        }
    }
}

// ---------------------------------------------------------------------------
// Kernel 2: fused partial scores. Block = 64 s-rows x 256 h (one h-half),
// 256 threads (4 waves). Wave wl: n-quarter (64 h), all 64 rows (mt=2 of 32).
// grid 2048, XCD-swizzled: lid = (bid&7)*256 + bid>>3 -> hh-pairs (lid 2i,
// 2i+1 <- bids differing by 8) land on the SAME XCD (bid%8 fixed) so the
// shared enc tile is an L2 hit for the second reader.
// LDS: Ahi 2x4K + Alo 2x4K + B 2x16K + u 1K + v 1K + partial 1K = 51KB
// -> 3 blocks/CU (reg cap was 4 anyway; pipeline replaces block overlap).
// ---------------------------------------------------------------------------
__global__ __launch_bounds__(256, 3) void score_kernel(
    const float* __restrict__ enc, const unsigned short* __restrict__ w2,
    const float* __restrict__ u, const float* __restrict__ v,
    float* __restrict__ scores_part) {
    __shared__ short Ahi[2][2048], Alo[2][2048];  // 64 rows x 32 k f16, chunk-major
    __shared__ short Bs[2][8192];                 // 256 h  x 32 k f16, chunk-major
    __shared__ float u_s[256], v_s[256];
    __shared__ float partial[4][64];

    const int tid  = threadIdx.x;
    const int wl   = tid >> 6, lane = tid & 63;
    const int col  = lane & 31;              // MFMA 32x32 col / A row
    const int bid  = blockIdx.x;
    const int lid  = ((bid & 7) << 8) + (bid >> 3);   // bijective XCD swizzle
    const int sblk = lid >> 1, hh = lid & 1;
    const int row0 = sblk * 64;
    const int b    = row0 >> 11;
    const float* encB = enc + (size_t)row0 * 1024;

    u_s[tid] = u[(b << 9) + (hh << 8) + tid];
    v_s[tid] = v[(hh << 8) + tid];

    f16v acc[2][2];
    #pragma unroll
    for (int mt = 0; mt < 2; ++mt)
        #pragma unroll
        for (int nt = 0; nt < 2; ++nt)
            #pragma unroll
            for (int r = 0; r < 16; ++r) acc[mt][nt][r] = 0.f;

    // A staging: thread t stages chunk t: mt=t>>7, kh=(t>>6)&1, l=t&63
    //   row = mt*32 + (l&31), kbase = kh*16 + (l>>5)*8
    const int s_mt = tid >> 7, s_kh = (tid >> 6) & 1, s_l = tid & 63;
    const int s_row = (s_mt << 5) + (s_l & 31);
    const int s_kb  = (s_kh << 4) + ((s_l >> 5) << 3);
    const float* aSrc = encB + (size_t)s_row * 1024 + s_kb;

    const char* bBase = (const char*)w2 + (hh << 14) + (wl << 12) + lane * 16;

// --- stage B(kkex) into Bs[buf] (wave-private slice): 4 gload_lds DMAs
#define STAGE_B(buf, kkex) do {                                               \
        const char* bs_ = bBase + (size_t)(kkex) * 32768;                     \
        char* bd_ = (char*)(&Bs[buf][0]) + (wl << 12);                        \
        gload_lds16(bs_,        bd_);                                         \
        gload_lds16(bs_ + 1024, bd_ + 1024);                                  \
        gload_lds16(bs_ + 2048, bd_ + 2048);                                  \
        gload_lds16(bs_ + 3072, bd_ + 3072);                                  \
    } while (0)

// --- cvt f32 regs -> f16 hi + lo residual, write A LDS buffer [buf]
#define CVT_WRITE_A(buf, r0, r1) do {                                         \
        half2v h01 = __builtin_amdgcn_cvt_pkrtz(r0[0], r0[1]);                \
        half2v h23 = __builtin_amdgcn_cvt_pkrtz(r0[2], r0[3]);                \
        half2v h45 = __builtin_amdgcn_cvt_pkrtz(r1[0], r1[1]);                \
        half2v h67 = __builtin_amdgcn_cvt_pkrtz(r1[2], r1[3]);                \
        half2v l01 = __builtin_amdgcn_cvt_pkrtz(r0[0] - (float)h01[0], r0[1] - (float)h01[1]); \
        half2v l23 = __builtin_amdgcn_cvt_pkrtz(r0[2] - (float)h23[0], r0[3] - (float)h23[1]); \
        half2v l45 = __builtin_amdgcn_cvt_pkrtz(r1[0] - (float)h45[0], r1[1] - (float)h45[1]); \
        half2v l67 = __builtin_amdgcn_cvt_pkrtz(r1[2] - (float)h67[0], r1[3] - (float)h67[1]); \
        uint4v hp_ = {bc2(h01), bc2(h23), bc2(h45), bc2(h67)};                \
        uint4v lp_ = {bc2(l01), bc2(l23), bc2(l45), bc2(l67)};                \
        ((uint4v*)(&Ahi[buf][0]))[tid] = hp_;                                 \
        ((uint4v*)(&Alo[buf][0]))[tid] = lp_;                                 \
    } while (0)

// --- 16 MFMAs for one K-step from buffers [buf]
#define COMPUTE(buf) do {                                                     \
        const half8* Ah8_ = (const half8*)(&Ahi[buf][0]);                     \
        const half8* Al8_ = (const half8*)(&Alo[buf][0]);                     \
        const half8* Bh8_ = (const half8*)(&Bs[buf][0]);                      \
        _Pragma("unroll")                                                     \
        for (int kh = 0; kh < 2; ++kh) {                                      \
            half8 ah0 = Ah8_[(kh << 6) + lane];                               \
            half8 ah1 = Ah8_[128 + (kh << 6) + lane];                         \
            half8 al0 = Al8_[(kh << 6) + lane];                               \
            half8 al1 = Al8_[128 + (kh << 6) + lane];                         \
            _Pragma("unroll")                                                 \
            for (int nt = 0; nt < 2; ++nt) {                                  \
                int ntl = (wl << 1) + nt;                                     \
                half8 b8 = Bh8_[((ntl << 1) + kh) * 64 + lane];               \
                acc[0][nt] = __builtin_amdgcn_mfma_f32_32x32x16_f16(ah0, b8, acc[0][nt], 0, 0, 0); \
                acc[0][nt] = __builtin_amdgcn_mfma_f32_32x32x16_f16(al0, b8, acc[0][nt], 0, 0, 0); \
                acc[1][nt] = __builtin_amdgcn_mfma_f32_32x32x16_f16(ah1, b8, acc[1][nt], 0, 0, 0); \
                acc[1][nt] = __builtin_amdgcn_mfma_f32_32x32x16_f16(al1, b8, acc[1][nt], 0, 0, 0); \
            }                                                                 \
        }                                                                     \
    } while (0)

// --- one K-step. Entry invariant: 2 VMEM outstanding (A-regs cx, loaded
// last step); A[buf],B[buf] staged & visible.
//   1) issue B(kk+1) -> Bs[buf^1]  (+4 -> 6)
//   2) issue A(kk+2) -> lx         (+2 -> 8)
//   3) CVT cx (data kk+1) -> A[buf^1]   (compiler waits vmcnt(6) for cx)
//   4) COMPUTE from [buf]
//   5) vmcnt(2): retires the 4 B DMAs (flight = CVT+COMPUTE ~800cy);
//      lgkm(0): A ds_writes visible. A(kk+2) crosses the barrier in flight.
//   6) s_barrier  (A-tile producer/consumer sync; B is wave-private)
#define ITER(kkex, buf, cx0, cx1, lx0, lx1) do {                              \
        int kb_ = (kkex) + 1; if (kb_ > 31) kb_ = 31;                         \
        STAGE_B((buf) ^ 1, kb_);                                              \
        MEMPIN;                                                               \
        int kn_ = (kkex) + 2; if (kn_ > 31) kn_ = 31;                         \
        lx0 = *(const f4*)(aSrc + (kn_ << 5));                                \
        lx1 = *(const f4*)(aSrc + (kn_ << 5) + 4);                            \
        MEMPIN;                                                               \
        CVT_WRITE_A((buf) ^ 1, cx0, cx1);                                     \
        COMPUTE(buf);                                                         \
        asm volatile("s_waitcnt vmcnt(2) lgkmcnt(0)" ::: "memory");           \
        __builtin_amdgcn_s_barrier();                                         \
        __builtin_amdgcn_sched_barrier(0);                                    \
    } while (0)

    // prologue: fill A[0],B[0]; leave A(1) regs in flight (entry invariant).
    f4 xa0 = *(const f4*)(aSrc);            // A(0)
    f4 xa1 = *(const f4*)(aSrc + 4);
    MEMPIN;
    STAGE_B(0, 0);
    MEMPIN;
    f4 xb0 = *(const f4*)(aSrc + 32);       // A(1)
    f4 xb1 = *(const f4*)(aSrc + 36);
    MEMPIN;
    CVT_WRITE_A(0, xa0, xa1);               // compiler waits vmcnt(6) for xa
    asm volatile("s_waitcnt vmcnt(2) lgkmcnt(0)" ::: "memory");  // B(0) landed
    __builtin_amdgcn_s_barrier();
    __builtin_amdgcn_sched_barrier(0);

    #pragma unroll 1
    for (int kk = 0; kk < 32; kk += 2) {
        ITER(kk,     0, xb0, xb1, xa0, xa1);
        ITER(kk + 1, 1, xa0, xa1, xb0, xb1);
    }

#undef ITER
#undef COMPUTE
#undef CVT_WRITE_A
#undef STAGE_B

    // --- epilogue: tanh, v-weight, reduce over 256 h (block-local)
    // C/D layout 32x32: col = lane&31, row = (reg&3) + 8*(reg>>2) + 4*(lane>>5)
    const int rhalf = (lane >> 5) << 2;
    #pragma unroll
    for (int mt = 0; mt < 2; ++mt) {
        #pragma unroll
        for (int reg = 0; reg < 16; ++reg) {
            float ssum = 0.f;
            #pragma unroll
            for (int nt = 0; nt < 2; ++nt) {
                int hl = (((wl << 1) + nt) << 5) + col;
                float x = u_s[hl] + acc[mt][nt][reg];
                float t = __expf(2.f * x);               // tanh via exp
                float th = 1.f - 2.f / (t + 1.f);
                ssum += v_s[hl] * th;
            }
            ssum += __shfl_xor(ssum, 1);
            ssum += __shfl_xor(ssum, 2);
            ssum += __shfl_xor(ssum, 4);
            ssum += __shfl_xor(ssum, 8);
            ssum += __shfl_xor(ssum, 16);
            if (col == 0)
                partial[wl][(mt << 5) + (reg & 3) + ((reg >> 2) << 3) + rhalf] = ssum;
        }
    }
    __syncthreads();
    if (tid < 64) {
        float s = partial[0][tid] + partial[1][tid] + partial[2][tid] + partial[3][tid];
        scores_part[(hh << 16) + row0 + tid] = s;
    }
}

// ---------------------------------------------------------------------------
// Kernel 3: softmax over s per batch. 32 blocks (one per b). Reads both
// score halves, writes NORMALIZED attn in-place into half-0 region.
// ---------------------------------------------------------------------------
__global__ __launch_bounds__(256) void softmax_kernel(float* scores_part) {
    __shared__ float wredm[4], wreds[4];
    const int t = threadIdx.x, b = blockIdx.x;
    const int wid = t >> 6, lane = t & 63;
    float* s0 = scores_part + ((size_t)b << 11);
    const float* s1 = s0 + 65536;

    float vals[8];
    float mx = -1e30f;
    #pragma unroll
    for (int i = 0; i < 8; ++i) {
        int idx = t + (i << 8);
        vals[i] = s0[idx] + s1[idx];
        mx = fmaxf(mx, vals[i]);
    }
    #pragma unroll
    for (int off = 1; off < 64; off <<= 1) mx = fmaxf(mx, __shfl_xor(mx, off));
    if (lane == 0) wredm[wid] = mx;
    __syncthreads();
    mx = fmaxf(fmaxf(wredm[0], wredm[1]), fmaxf(wredm[2], wredm[3]));

    float e[8], lsum = 0.f;
    #pragma unroll
    for (int i = 0; i < 8; ++i) {
        e[i] = __expf(vals[i] - mx);
        lsum += e[i];
    }
    #pragma unroll
    for (int off = 1; off < 64; off <<= 1) lsum += __shfl_xor(lsum, off);
    if (lane == 0) wreds[wid] = lsum;
    __syncthreads();
    const float inv = 1.f / (wreds[0] + wreds[1] + wreds[2] + wreds[3]);
    #pragma unroll
    for (int i = 0; i < 8; ++i) s0[t + (i << 8)] = e[i] * inv;
}

// ---------------------------------------------------------------------------
// Kernel 4: per-(b, 64-row s-chunk) partial context, 1024 blocks.
// Pure stream: attn (normalized) staged 64 floats in LDS.
// ---------------------------------------------------------------------------
__global__ __launch_bounds__(256) void ctx_partial_kernel(
    const float* __restrict__ enc, const float* __restrict__ attn,
    float* __restrict__ partials) {
    __shared__ float a_s[64];
    const int t = threadIdx.x;
    const int b = blockIdx.x >> 5, sc = blockIdx.x & 31;
    if (t < 64) a_s[t] = attn[((size_t)b << 11) + (sc << 6) + t];
    __syncthreads();

    f4 a0 = (f4){0.f, 0.f, 0.f, 0.f};
    f4 a1 = (f4){0.f, 0.f, 0.f, 0.f};
    f4 a2 = (f4){0.f, 0.f, 0.f, 0.f};
    f4 a3 = (f4){0.f, 0.f, 0.f, 0.f};
    const f4* erow = ((const f4*)(enc + ((size_t)b * 2048 + (sc << 6)) * 1024)) + t;
    #pragma unroll 4
    for (int i = 0; i < 64; i += 4) {
        a0 += a_s[i]     * erow[(size_t)i << 8];
        a1 += a_s[i + 1] * erow[((size_t)(i + 1)) << 8];
        a2 += a_s[i + 2] * erow[((size_t)(i + 2)) << 8];
        a3 += a_s[i + 3] * erow[((size_t)(i + 3)) << 8];
    }
    f4 a = (a0 + a1) + (a2 + a3);
    f4* dst = (f4*)(partials + (((size_t)(sc << 5) + b) << 10));
    dst[t] = a;
}

// ---------------------------------------------------------------------------
// Kernel 5: reduce 32 s-chunk partials -> context
// ---------------------------------------------------------------------------
__global__ __launch_bounds__(256) void ctx_reduce_kernel(
    const float* __restrict__ partials, float* __restrict__ out) {
    int i = blockIdx.x * 256 + threadIdx.x;   // 0..32767  (b*1024 + d)
    float s = 0.f;
    #pragma unroll
    for (int sc = 0; sc < 32; ++sc) s += partials[sc * 32768 + i];
    out[i] = s;
}

// ---------------------------------------------------------------------------
extern "C" void kernel_launch(void* const* d_in, const int* in_sizes, int n_in,
                              void* d_out, int out_size, void* d_ws, size_t ws_size,
                              hipStream_t stream) {
    const float* hidden = (const float*)d_in[0];   // [32,1024]
    const float* enc    = (const float*)d_in[1];   // [32,2048,1024]
    const float* W      = (const float*)d_in[2];   // [512,2048]
    const float* bias   = (const float*)d_in[3];   // [512]
    const float* v      = (const float*)d_in[4];   // [512]
    float* out = (float*)d_out;                    // [32,1024]
    char* ws = (char*)d_ws;

    // ws layout (bytes):
    float* u            = (float*)(ws);                    //    65536
    float* scores_part  = (float*)(ws + 65536);            //   524288 (2 halves; half0 becomes attn)
    float* partials     = (float*)(ws + 589824);           //  4194304
    unsigned short* w2  = (unsigned short*)(ws + 4784128); //  1048576  (~5.8MB)

    prep_kernel<<<512, 256, 0, stream>>>(hidden, W, bias, u, w2);
    score_kernel<<<2048, 256, 0, stream>>>(enc, w2, u, v, scores_part);
    softmax_kernel<<<32, 256, 0, stream>>>(scores_part);
    ctx_partial_kernel<<<1024, 256, 0, stream>>>(enc, scores_part, partials);
    ctx_reduce_kernel<<<128, 256, 0, stream>>>(partials, out);
}

// Round 7
// 517.404 us; speedup vs baseline: 1.0350x; 1.0350x over previous
//
#include <hip/hip_runtime.h>

// ---------------------------------------------------------------------------
// Attention (Bahdanau): B=32, S=2048, H=512, 2H=1024, 4H=2048
//   u[b,h]      = bias[h] + dot(hidden[b,:1024], W[h,:1024])      (fp32, tiny)
//   scores[b,s] = sum_h v[h]*tanh(u[b,h] + dot(enc[b,s,:], W[h,1024:]))
//   attn        = softmax_s(scores);  context[b,d] = sum_s attn[b,s]*enc[b,s,d]
// R12: score = proven R7 structure (27.6KB LDS, 2 barriers, ~41% occ, 207us)
//   + R11's XCD swizzle (proven: FETCH 267->143MB; free). Deep-pipeline line
//   retired (R11 kill-criterion: 222us @ 31% occ - occupancy beats pipelining
//   on this structure; 28-30% of f16 peak = this structure's ceiling).
// Back end collapsed: softmax+context+reduce fused into ONE kernel
//   (256 blocks x 512 thr; per-block local softmax is 16KB+2K exp, trivial;
//   streams enc once, writes out directly). Removes 2 launches, 4MB partials
//   buffer, 8MB HBM roundtrip -> attacks the ~150-200us of launch-gap/
//   roundtrip implied by (total 519 - score 207 - estimates).
// ---------------------------------------------------------------------------

typedef __fp16   half2v __attribute__((ext_vector_type(2)));   // pkrtz result type
typedef _Float16 half8  __attribute__((ext_vector_type(8)));   // MFMA operand type
typedef __attribute__((ext_vector_type(4)))  float f4;
typedef __attribute__((ext_vector_type(16))) float f16v;
typedef __attribute__((ext_vector_type(4)))  unsigned int uint4v;

__device__ __forceinline__ void gload_lds16(const void* g, void* l) {
    __builtin_amdgcn_global_load_lds(
        (const __attribute__((address_space(1))) unsigned int*)g,
        (__attribute__((address_space(3))) unsigned int*)l, 16, 0, 0);
}
__device__ __forceinline__ unsigned int bc2(half2v h) {
    return __builtin_bit_cast(unsigned int, h);
}

// ---------------------------------------------------------------------------
// Kernel 1: W2 f16 fragment-major pack (blocks 0..255) + u[b,h] (blocks
// 256..511, coalesced: wave reads whole W rows, hidden staged in LDS,
// 64-lane shuffle reduce). Pack: chunk g = kk*2048 + ntg*128 + kh*64 + l
// holds 8 f16: W[h = ntg*32 + (l&31)][1024 + kk*32 + kh*16 + (l>>5)*8 + j].
// ---------------------------------------------------------------------------
__global__ __launch_bounds__(256) void prep_kernel(
    const float* __restrict__ hidden, const float* __restrict__ W,
    const float* __restrict__ bias, float* __restrict__ u,
    unsigned short* __restrict__ w2) {
    __shared__ float hid_s[1024];
    if (blockIdx.x < 256) {
        int g = blockIdx.x * 256 + threadIdx.x;   // 0..65535 chunks
        int kk = g >> 11, id = g & 2047;
        int ntg = id >> 7, kh = (id >> 6) & 1, l = id & 63;
        int h = (ntg << 5) + (l & 31);
        int kg = 1024 + (kk << 5) + (kh << 4) + ((l >> 5) << 3);
        const float* src = W + (size_t)h * 2048 + kg;
        f4 x0 = *(const f4*)src;
        f4 x1 = *(const f4*)(src + 4);
        half8 vh;
        #pragma unroll
        for (int j = 0; j < 4; ++j) vh[j] = (_Float16)x0[j];      // RN
        #pragma unroll
        for (int j = 0; j < 4; ++j) vh[4 + j] = (_Float16)x1[j];  // RN
        ((half8*)w2)[g] = vh;
    } else {
        // u-part: block = (b, 64-h group). Coalesced W-row reads (1KB/instr).
        const int t = threadIdx.x;
        const int blk = (int)blockIdx.x - 256;
        const int b = blk >> 3, hg = blk & 7;
        ((f4*)hid_s)[t] = ((const f4*)(hidden + ((size_t)b << 10)))[t];
        __syncthreads();
        const int w = t >> 6, lane = t & 63;
        const f4* hid4 = (const f4*)hid_s;
        #pragma unroll 2
        for (int i = 0; i < 16; ++i) {
            int h = (hg << 6) + (w << 4) + i;
            const f4* wr = (const f4*)(W + (size_t)h * 2048);
            float p = 0.f;
            #pragma unroll
            for (int i2 = 0; i2 < 4; ++i2) {
                f4 w4 = wr[lane + (i2 << 6)];
                f4 h4 = hid4[lane + (i2 << 6)];
                p += w4[0]*h4[0] + w4[1]*h4[1] + w4[2]*h4[2] + w4[3]*h4[3];
            }
            #pragma unroll
            for (int off = 1; off < 64; off <<= 1) p += __shfl_xor(p, off);
            if (lane == 0) u[((size_t)b << 9) + h] = bias[h] + p;
        }
    }
}

// ---------------------------------------------------------------------------
// Kernel 2: fused partial scores. Block = 64 s-rows x 256 h (one h-half),
// 256 threads (4 waves). Wave wl: n-quarter (64 h), all 64 rows (mt=2 of 32).
// grid 2048, XCD-swizzled: lid = (bid&7)*256 + bid>>3 -> hh-pairs (lids 2i,
// 2i+1 come from bids differing by 8 -> same XCD slot pattern) share the enc
// tile in L2/L3 (R11: FETCH 267->143MB).
// LDS: Ahi 4K + Alo 4K + B 16K + u 1K + v 1K + partial 1K = 27KB (R7
// structure, ~41% occ: implicit multi-block overlap beats explicit dbuf).
// ---------------------------------------------------------------------------
__global__ __launch_bounds__(256, 3) void score_kernel(
    const float* __restrict__ enc, const unsigned short* __restrict__ w2,
    const float* __restrict__ u, const float* __restrict__ v,
    float* __restrict__ scores_part) {
    __shared__ short Ahi[2048], Alo[2048];   // 64 rows x 32 k f16, chunk-major
    __shared__ short Bs[8192];               // 256 h  x 32 k f16, chunk-major
    __shared__ float u_s[256], v_s[256];
    __shared__ float partial[4][64];

    const int tid  = threadIdx.x;
    const int wl   = tid >> 6, lane = tid & 63;
    const int col  = lane & 31;              // MFMA 32x32 col / A row
    const int bid  = blockIdx.x;
    const int lid  = ((bid & 7) << 8) + (bid >> 3);   // bijective XCD swizzle
    const int sblk = lid >> 1, hh = lid & 1;
    const int row0 = sblk * 64;
    const int b    = row0 >> 11;
    const float* encB = enc + (size_t)row0 * 1024;

    u_s[tid] = u[(b << 9) + (hh << 8) + tid];
    v_s[tid] = v[(hh << 8) + tid];

    f16v acc[2][2];
    #pragma unroll
    for (int mt = 0; mt < 2; ++mt)
        #pragma unroll
        for (int nt = 0; nt < 2; ++nt)
            #pragma unroll
            for (int r = 0; r < 16; ++r) acc[mt][nt][r] = 0.f;

    // A staging: thread t stages chunk t: mt=t>>7, kh=(t>>6)&1, l=t&63
    //   row = mt*32 + (l&31), kbase = kh*16 + (l>>5)*8
    const int s_mt = tid >> 7, s_kh = (tid >> 6) & 1, s_l = tid & 63;
    const int s_row = (s_mt << 5) + (s_l & 31);
    const int s_kb  = (s_kh << 4) + ((s_l >> 5) << 3);
    const float* aSrc = encB + (size_t)s_row * 1024 + s_kb;

    const half8* Ah8 = (const half8*)Ahi;
    const half8* Al8 = (const half8*)Alo;
    const half8* Bh8 = (const half8*)Bs;

    for (int kk = 0; kk < 32; ++kk) {
        // prefetch A source before barrier (hide global latency)
        f4 x0 = *(const f4*)(aSrc + (kk << 5));
        f4 x1 = *(const f4*)(aSrc + (kk << 5) + 4);
        __syncthreads();   // previous iter's LDS reads complete
        // --- stage A: f32 -> f16 hi (pkrtz) + lo (residual, pkrtz)
        {
            half2v h01 = __builtin_amdgcn_cvt_pkrtz(x0[0], x0[1]);
            half2v h23 = __builtin_amdgcn_cvt_pkrtz(x0[2], x0[3]);
            half2v h45 = __builtin_amdgcn_cvt_pkrtz(x1[0], x1[1]);
            half2v h67 = __builtin_amdgcn_cvt_pkrtz(x1[2], x1[3]);
            half2v l01 = __builtin_amdgcn_cvt_pkrtz(x0[0] - (float)h01[0], x0[1] - (float)h01[1]);
            half2v l23 = __builtin_amdgcn_cvt_pkrtz(x0[2] - (float)h23[0], x0[3] - (float)h23[1]);
            half2v l45 = __builtin_amdgcn_cvt_pkrtz(x1[0] - (float)h45[0], x1[1] - (float)h45[1]);
            half2v l67 = __builtin_amdgcn_cvt_pkrtz(x1[2] - (float)h67[0], x1[3] - (float)h67[1]);
            uint4v hp = {bc2(h01), bc2(h23), bc2(h45), bc2(h67)};
            uint4v lp = {bc2(l01), bc2(l23), bc2(l45), bc2(l67)};
            ((uint4v*)Ahi)[tid] = hp;
            ((uint4v*)Alo)[tid] = lp;
        }
        // --- stage B (w2 f16 packed) via global_load_lds: 16KB, contiguous
        {
            const char* bsrc = (const char*)w2 + (size_t)kk * 32768 + (hh << 14)
                               + (wl << 12) + lane * 16;
            char* bdst = (char*)Bs + (wl << 12);
            #pragma unroll
            for (int i = 0; i < 4; ++i)
                gload_lds16(bsrc + (i << 10), bdst + (i << 10));
        }
        __syncthreads();   // staging complete
        // --- compute: 2 kh x (2 mt x 2 nt x 2 hi/lo) MFMAs
        #pragma unroll
        for (int kh = 0; kh < 2; ++kh) {
            half8 ah0 = Ah8[(kh << 6) + lane];
            half8 ah1 = Ah8[128 + (kh << 6) + lane];
            half8 al0 = Al8[(kh << 6) + lane];
            half8 al1 = Al8[128 + (kh << 6) + lane];
            #pragma unroll
            for (int nt = 0; nt < 2; ++nt) {
                int ntl = (wl << 1) + nt;
                half8 b8 = Bh8[((ntl << 1) + kh) * 64 + lane];
                acc[0][nt] = __builtin_amdgcn_mfma_f32_32x32x16_f16(ah0, b8, acc[0][nt], 0, 0, 0);
                acc[0][nt] = __builtin_amdgcn_mfma_f32_32x32x16_f16(al0, b8, acc[0][nt], 0, 0, 0);
                acc[1][nt] = __builtin_amdgcn_mfma_f32_32x32x16_f16(ah1, b8, acc[1][nt], 0, 0, 0);
                acc[1][nt] = __builtin_amdgcn_mfma_f32_32x32x16_f16(al1, b8, acc[1][nt], 0, 0, 0);
            }
        }
    }
    // --- epilogue: tanh, v-weight, reduce over 256 h (block-local)
    // C/D layout 32x32: col = lane&31, row = (reg&3) + 8*(reg>>2) + 4*(lane>>5)
    const int rhalf = (lane >> 5) << 2;
    #pragma unroll
    for (int mt = 0; mt < 2; ++mt) {
        #pragma unroll
        for (int reg = 0; reg < 16; ++reg) {
            float ssum = 0.f;
            #pragma unroll
            for (int nt = 0; nt < 2; ++nt) {
                int hl = (((wl << 1) + nt) << 5) + col;
                float x = u_s[hl] + acc[mt][nt][reg];
                float t = __expf(2.f * x);               // tanh via exp
                float th = 1.f - 2.f / (t + 1.f);
                ssum += v_s[hl] * th;
            }
            ssum += __shfl_xor(ssum, 1);
            ssum += __shfl_xor(ssum, 2);
            ssum += __shfl_xor(ssum, 4);
            ssum += __shfl_xor(ssum, 8);
            ssum += __shfl_xor(ssum, 16);
            if (col == 0)
                partial[wl][(mt << 5) + (reg & 3) + ((reg >> 2) << 3) + rhalf] = ssum;
        }
    }
    __syncthreads();
    if (tid < 64) {
        float s = partial[0][tid] + partial[1][tid] + partial[2][tid] + partial[3][tid];
        scores_part[(hh << 16) + row0 + tid] = s;
    }
}

// ---------------------------------------------------------------------------
// Kernel 3: FUSED softmax + context. 256 blocks x 512 threads.
// Block = (b, dg): one batch row, 128-float d-slice. Local softmax over the
// full 2048 scores (16KB read + 2K exp, x8 redundant per b - trivial), then
// stream enc[b][:, dg*128:+128] (1MB) with 4 independent f4 accumulators,
// write context directly to out. No partials buffer, no extra launches.
// ---------------------------------------------------------------------------
__global__ __launch_bounds__(512) void ctx_kernel(
    const float* __restrict__ enc, const float* __restrict__ scores_part,
    float* __restrict__ out) {
    __shared__ float p_s[2048];
    __shared__ float wredm[8], wreds[8];
    __shared__ f4 red[16][32];
    const int t = threadIdx.x;
    const int b = blockIdx.x >> 3, dg = blockIdx.x & 7;
    const int wid = t >> 6, lane = t & 63;
    const float* s0 = scores_part + ((size_t)b << 11);
    const float* s1 = s0 + 65536;

    // --- softmax over 2048 scores (4 per thread)
    float vals[4];
    float mx = -1e30f;
    #pragma unroll
    for (int i = 0; i < 4; ++i) {
        int idx = t + (i << 9);
        vals[i] = s0[idx] + s1[idx];
        mx = fmaxf(mx, vals[i]);
    }
    #pragma unroll
    for (int off = 1; off < 64; off <<= 1) mx = fmaxf(mx, __shfl_xor(mx, off));
    if (lane == 0) wredm[wid] = mx;
    __syncthreads();
    #pragma unroll
    for (int i = 0; i < 8; ++i) mx = fmaxf(mx, wredm[i]);

    float e[4], lsum = 0.f;
    #pragma unroll
    for (int i = 0; i < 4; ++i) {
        e[i] = __expf(vals[i] - mx);
        lsum += e[i];
    }
    #pragma unroll
    for (int off = 1; off < 64; off <<= 1) lsum += __shfl_xor(lsum, off);
    if (lane == 0) wreds[wid] = lsum;
    __syncthreads();
    float tot = 0.f;
    #pragma unroll
    for (int i = 0; i < 8; ++i) tot += wreds[i];
    const float inv = 1.f / tot;
    #pragma unroll
    for (int i = 0; i < 4; ++i) p_s[t + (i << 9)] = e[i] * inv;
    __syncthreads();

    // --- stream enc slice: rows r = i*16 + rg, f4-cols dg*32 + col
    const int col = t & 31, rg = t >> 5;     // rg 0..15
    const f4* e4 = (const f4*)enc;
    const size_t base = (((size_t)b << 11) << 8) + (dg << 5) + col; // (b*2048)*256 + ...
    f4 a0 = (f4){0.f,0.f,0.f,0.f}, a1 = (f4){0.f,0.f,0.f,0.f};
    f4 a2 = (f4){0.f,0.f,0.f,0.f}, a3 = (f4){0.f,0.f,0.f,0.f};
    #pragma unroll 2
    for (int i = 0; i < 128; i += 4) {
        int r0 = ((i + 0) << 4) + rg;
        int r1 = ((i + 1) << 4) + rg;
        int r2 = ((i + 2) << 4) + rg;
        int r3 = ((i + 3) << 4) + rg;
        a0 += p_s[r0] * e4[base + ((size_t)r0 << 8)];
        a1 += p_s[r1] * e4[base + ((size_t)r1 << 8)];
        a2 += p_s[r2] * e4[base + ((size_t)r2 << 8)];
        a3 += p_s[r3] * e4[base + ((size_t)r3 << 8)];
    }
    red[rg][col] = (a0 + a1) + (a2 + a3);
    __syncthreads();
    if (t < 32) {
        f4 s = red[0][t];
        #pragma unroll
        for (int g = 1; g < 16; ++g) s += red[g][t];
        ((f4*)out)[(b << 8) + (dg << 5) + t] = s;
    }
}

// ---------------------------------------------------------------------------
extern "C" void kernel_launch(void* const* d_in, const int* in_sizes, int n_in,
                              void* d_out, int out_size, void* d_ws, size_t ws_size,
                              hipStream_t stream) {
    const float* hidden = (const float*)d_in[0];   // [32,1024]
    const float* enc    = (const float*)d_in[1];   // [32,2048,1024]
    const float* W      = (const float*)d_in[2];   // [512,2048]
    const float* bias   = (const float*)d_in[3];   // [512]
    const float* v      = (const float*)d_in[4];   // [512]
    float* out = (float*)d_out;                    // [32,1024]
    char* ws = (char*)d_ws;

    // ws layout (bytes):
    float* u            = (float*)(ws);                    //    65536
    float* scores_part  = (float*)(ws + 65536);            //   524288 (2 halves)
    unsigned short* w2  = (unsigned short*)(ws + 589824);  //  1048576  (~1.6MB)

    prep_kernel<<<512, 256, 0, stream>>>(hidden, W, bias, u, w2);
    score_kernel<<<2048, 256, 0, stream>>>(enc, w2, u, v, scores_part);
    ctx_kernel<<<256, 512, 0, stream>>>(enc, scores_part, out);
}